// Round 1
// baseline (13087.846 us; speedup 1.0000x reference)
//
#include <hip/hip_runtime.h>

#define TLEN 32768
#define NB 4
#define NLAYER 30

__device__ __forceinline__ float fast_sigmoid(float x) {
  return 1.0f / (1.0f + __expf(-x));
}
__device__ __forceinline__ float fast_tanh(float x) {
  return 2.0f / (1.0f + __expf(-2.0f * x)) - 1.0f;
}

// acc[0..3] += W (float4 over k) dot X rows (float4 over t)
#define ACC4(A, W, X0, X1, X2, X3)                                          \
  (A)[0] += (W).x*(X0).x + (W).y*(X1).x + (W).z*(X2).x + (W).w*(X3).x;      \
  (A)[1] += (W).x*(X0).y + (W).y*(X1).y + (W).z*(X2).y + (W).w*(X3).y;      \
  (A)[2] += (W).x*(X0).z + (W).y*(X1).z + (W).z*(X2).z + (W).w*(X3).z;      \
  (A)[3] += (W).x*(X0).w + (W).y*(X1).w + (W).z*(X2).w + (W).w*(X3).w;

// x0[b][r][t] = cw[r]*y[b][t] + cb[r]
__global__ __launch_bounds__(256) void wn_causal_k(
    const float* __restrict__ y, const float* __restrict__ cw,
    const float* __restrict__ cb, float* __restrict__ x0) {
  int b = blockIdx.x >> 7;                      // T/256 = 128 blocks per batch
  int t = ((blockIdx.x & 127) << 8) + threadIdx.x;
  float yv = y[(size_t)b * TLEN + t];
  float* xp = x0 + (size_t)b * 64 * TLEN + t;
#pragma unroll
  for (int r = 0; r < 64; ++r) xp[(size_t)r * TLEN] = cw[r] * yv + cb[r];
}

// One WaveNet layer over a 64-t tile per block.
__global__ __launch_bounds__(256) void wn_layer_k(
    const float* __restrict__ xin, float* __restrict__ xout,
    float* __restrict__ skip, const float* __restrict__ filt,
    const float* __restrict__ gate, const float* __restrict__ resw,
    const float* __restrict__ skipw, int dil, int first) {
  __shared__ __align__(16) float Xs[8192];   // [k=2r+tap][t] 128x64
  __shared__ __align__(16) float buf[8192];  // weight chunks / out tile

  const int tid = threadIdx.x;
  const int b = blockIdx.x >> 9;             // T/64 = 512 tiles per batch
  const int t0 = (blockIdx.x & 511) << 6;
  const float* xb = xin + (size_t)b * 64 * TLEN;

  // Stage X: row 2r+0 = x[t-d] (zero-padded), row 2r+1 = x[t]
  for (int idx = tid; idx < 8192; idx += 256) {
    int k = idx >> 6, t = idx & 63;
    int r = k >> 1;
    int ts = t0 + t - ((k & 1) ? 0 : dil);
    Xs[idx] = (ts >= 0) ? xb[(size_t)r * TLEN + ts] : 0.0f;
  }

  const int tc = tid >> 4;  // 0..15 -> 4 output channels each
  const int tt = tid & 15;  // 0..15 -> 4 t each
  const int c0 = tc << 2;
  const int tl = tt << 2;

  float pf[16], pg[16];
#pragma unroll
  for (int i = 0; i < 16; ++i) { pf[i] = 0.f; pg[i] = 0.f; }

  // Conv over k=0..127 in two halves; filt chunk in buf[0:4096], gate in buf[4096:]
  for (int kh = 0; kh < 128; kh += 64) {
    __syncthreads();
    for (int idx = tid; idx < 4096; idx += 256) {
      int c = idx >> 6, kk = idx & 63;
      buf[idx]        = filt[c * 128 + kh + kk];
      buf[4096 + idx] = gate[c * 128 + kh + kk];
    }
    __syncthreads();
#pragma unroll 2
    for (int kk = 0; kk < 64; kk += 4) {
      float4 xv0 = *(const float4*)&Xs[(kh + kk + 0) * 64 + tl];
      float4 xv1 = *(const float4*)&Xs[(kh + kk + 1) * 64 + tl];
      float4 xv2 = *(const float4*)&Xs[(kh + kk + 2) * 64 + tl];
      float4 xv3 = *(const float4*)&Xs[(kh + kk + 3) * 64 + tl];
#pragma unroll
      for (int ic = 0; ic < 4; ++ic) {
        float4 wf = *(const float4*)&buf[(c0 + ic) * 64 + kk];
        float4 wg = *(const float4*)&buf[4096 + (c0 + ic) * 64 + kk];
        ACC4(pf + ic * 4, wf, xv0, xv1, xv2, xv3)
        ACC4(pg + ic * 4, wg, xv0, xv1, xv2, xv3)
      }
    }
  }

  __syncthreads();
  // out = tanh(pf)*sigmoid(pg) -> buf[0:4096] as [d][t]; res_w -> buf[4096:]
#pragma unroll
  for (int ic = 0; ic < 4; ++ic) {
    float4 o;
    o.x = fast_tanh(pf[ic * 4 + 0]) * fast_sigmoid(pg[ic * 4 + 0]);
    o.y = fast_tanh(pf[ic * 4 + 1]) * fast_sigmoid(pg[ic * 4 + 1]);
    o.z = fast_tanh(pf[ic * 4 + 2]) * fast_sigmoid(pg[ic * 4 + 2]);
    o.w = fast_tanh(pf[ic * 4 + 3]) * fast_sigmoid(pg[ic * 4 + 3]);
    *(float4*)&buf[(c0 + ic) * 64 + tl] = o;
  }
  for (int idx = tid; idx < 4096; idx += 256) buf[4096 + idx] = resw[idx];
  __syncthreads();

  // Residual: xout = xc + res_w @ out
  {
    float xa[16];
#pragma unroll
    for (int ir = 0; ir < 4; ++ir) {
      float4 xc = *(const float4*)&Xs[(((c0 + ir) << 1) + 1) * 64 + tl];
      xa[ir * 4 + 0] = xc.x; xa[ir * 4 + 1] = xc.y;
      xa[ir * 4 + 2] = xc.z; xa[ir * 4 + 3] = xc.w;
    }
#pragma unroll 2
    for (int kk = 0; kk < 64; kk += 4) {
      float4 ov0 = *(const float4*)&buf[(kk + 0) * 64 + tl];
      float4 ov1 = *(const float4*)&buf[(kk + 1) * 64 + tl];
      float4 ov2 = *(const float4*)&buf[(kk + 2) * 64 + tl];
      float4 ov3 = *(const float4*)&buf[(kk + 3) * 64 + tl];
#pragma unroll
      for (int ir = 0; ir < 4; ++ir) {
        float4 w = *(const float4*)&buf[4096 + (c0 + ir) * 64 + kk];
        ACC4(xa + ir * 4, w, ov0, ov1, ov2, ov3)
      }
    }
    float* xo = xout + (size_t)b * 64 * TLEN + t0 + tl;
#pragma unroll
    for (int ir = 0; ir < 4; ++ir) {
      float4 v;
      v.x = xa[ir * 4 + 0]; v.y = xa[ir * 4 + 1];
      v.z = xa[ir * 4 + 2]; v.w = xa[ir * 4 + 3];
      *(float4*)&xo[(size_t)(c0 + ir) * TLEN] = v;
    }
  }

  // Skip: 4 sub-blocks of 64 s-rows; skip += skip_w @ out (write on layer 0)
  for (int sb = 0; sb < 4; ++sb) {
    __syncthreads();
    for (int idx = tid; idx < 4096; idx += 256)
      buf[4096 + idx] = skipw[sb * 4096 + idx];
    __syncthreads();
    float sa[16];
#pragma unroll
    for (int i = 0; i < 16; ++i) sa[i] = 0.f;
#pragma unroll 2
    for (int kk = 0; kk < 64; kk += 4) {
      float4 ov0 = *(const float4*)&buf[(kk + 0) * 64 + tl];
      float4 ov1 = *(const float4*)&buf[(kk + 1) * 64 + tl];
      float4 ov2 = *(const float4*)&buf[(kk + 2) * 64 + tl];
      float4 ov3 = *(const float4*)&buf[(kk + 3) * 64 + tl];
#pragma unroll
      for (int is = 0; is < 4; ++is) {
        float4 w = *(const float4*)&buf[4096 + (c0 + is) * 64 + kk];
        ACC4(sa + is * 4, w, ov0, ov1, ov2, ov3)
      }
    }
    float* sp = skip + ((size_t)(b * 256 + sb * 64 + c0)) * TLEN + t0 + tl;
    if (first) {
#pragma unroll
      for (int is = 0; is < 4; ++is) {
        float4 v;
        v.x = sa[is * 4 + 0]; v.y = sa[is * 4 + 1];
        v.z = sa[is * 4 + 2]; v.w = sa[is * 4 + 3];
        *(float4*)&sp[(size_t)is * TLEN] = v;
      }
    } else {
#pragma unroll
      for (int is = 0; is < 4; ++is) {
        float4 v = *(const float4*)&sp[(size_t)is * TLEN];
        v.x += sa[is * 4 + 0]; v.y += sa[is * 4 + 1];
        v.z += sa[is * 4 + 2]; v.w += sa[is * 4 + 3];
        *(float4*)&sp[(size_t)is * TLEN] = v;
      }
    }
  }
}

// Head: relu(skip) -> end1 -> relu -> end2 -> out[b][t][c], 32-t tile per block.
__global__ __launch_bounds__(256) void wn_end_k(
    const float* __restrict__ skip, const float* __restrict__ w1,
    const float* __restrict__ b1, const float* __restrict__ w2,
    const float* __restrict__ b2, float* __restrict__ out) {
  __shared__ __align__(16) float h[8192];   // [s][t] 256x32 (reused for h2)
  __shared__ __align__(16) float wc[8192];  // weight chunk [o][32k]

  const int tid = threadIdx.x;
  const int b = blockIdx.x >> 10;           // T/32 = 1024 tiles per batch
  const int t0 = (blockIdx.x & 1023) << 5;
  const float* sp = skip + (size_t)b * 256 * TLEN + t0;
  for (int idx = tid; idx < 8192; idx += 256) {
    int s = idx >> 5, t = idx & 31;
    h[idx] = fmaxf(sp[(size_t)s * TLEN + t], 0.f);
  }
  const int to = tid >> 3, tt = tid & 7;
  const int tl = tt << 2;

  float acc[32];
#pragma unroll
  for (int i = 0; i < 32; ++i) acc[i] = 0.f;

  // GEMM1: k-chunks of 32 over 256
  for (int ko = 0; ko < 8; ++ko) {
    __syncthreads();
    for (int idx = tid; idx < 8192; idx += 256) {
      int o = idx >> 5, kk = idx & 31;
      wc[idx] = w1[o * 256 + (ko << 5) + kk];
    }
    __syncthreads();
#pragma unroll 2
    for (int kk = 0; kk < 32; kk += 4) {
      int kb = (ko << 5) + kk;
      float4 hv0 = *(const float4*)&h[(kb + 0) * 32 + tl];
      float4 hv1 = *(const float4*)&h[(kb + 1) * 32 + tl];
      float4 hv2 = *(const float4*)&h[(kb + 2) * 32 + tl];
      float4 hv3 = *(const float4*)&h[(kb + 3) * 32 + tl];
#pragma unroll
      for (int j = 0; j < 8; ++j) {
        int o = to + (j << 5);  // stride-32 o mapping: 2-way banks (free)
        float4 w = *(const float4*)&wc[o * 32 + kk];
        ACC4(acc + j * 4, w, hv0, hv1, hv2, hv3)
      }
    }
  }
  __syncthreads();
  // h2 = relu(acc + b1) back into h
#pragma unroll
  for (int j = 0; j < 8; ++j) {
    int o = to + (j << 5);
    float bb = b1[o];
    float4 v;
    v.x = fmaxf(acc[j * 4 + 0] + bb, 0.f);
    v.y = fmaxf(acc[j * 4 + 1] + bb, 0.f);
    v.z = fmaxf(acc[j * 4 + 2] + bb, 0.f);
    v.w = fmaxf(acc[j * 4 + 3] + bb, 0.f);
    *(float4*)&h[o * 32 + tl] = v;
    acc[j * 4 + 0] = 0.f; acc[j * 4 + 1] = 0.f;
    acc[j * 4 + 2] = 0.f; acc[j * 4 + 3] = 0.f;
  }
  // GEMM2
  for (int ko = 0; ko < 8; ++ko) {
    __syncthreads();
    for (int idx = tid; idx < 8192; idx += 256) {
      int o = idx >> 5, kk = idx & 31;
      wc[idx] = w2[o * 256 + (ko << 5) + kk];
    }
    __syncthreads();
#pragma unroll 2
    for (int kk = 0; kk < 32; kk += 4) {
      int kb = (ko << 5) + kk;
      float4 hv0 = *(const float4*)&h[(kb + 0) * 32 + tl];
      float4 hv1 = *(const float4*)&h[(kb + 1) * 32 + tl];
      float4 hv2 = *(const float4*)&h[(kb + 2) * 32 + tl];
      float4 hv3 = *(const float4*)&h[(kb + 3) * 32 + tl];
#pragma unroll
      for (int j = 0; j < 8; ++j) {
        int o = to + (j << 5);
        float4 w = *(const float4*)&wc[o * 32 + kk];
        ACC4(acc + j * 4, w, hv0, hv1, hv2, hv3)
      }
    }
  }
  float* op = out + ((size_t)b * TLEN + t0) * 256;
#pragma unroll
  for (int j = 0; j < 8; ++j) {
    int o = to + (j << 5);
    float bb = b2[o];
#pragma unroll
    for (int it = 0; it < 4; ++it)
      op[(size_t)(tl + it) * 256 + o] = acc[j * 4 + it] + bb;
  }
}

extern "C" void kernel_launch(void* const* d_in, const int* in_sizes, int n_in,
                              void* d_out, int out_size, void* d_ws,
                              size_t ws_size, hipStream_t stream) {
  (void)in_sizes; (void)n_in; (void)out_size; (void)ws_size;
  const float* y     = (const float*)d_in[0];
  const float* cw    = (const float*)d_in[1];
  const float* cb    = (const float*)d_in[2];
  const float* filt  = (const float*)d_in[3];
  const float* gate  = (const float*)d_in[4];
  const float* resw  = (const float*)d_in[5];
  const float* skipw = (const float*)d_in[6];
  const float* w1    = (const float*)d_in[7];
  const float* b1    = (const float*)d_in[8];
  const float* w2    = (const float*)d_in[9];
  const float* b2    = (const float*)d_in[10];
  float* out = (float*)d_out;

  // ws: x0 (32MB) | x1 (32MB) | skip (128MB)  => 192MB total
  float* x0   = (float*)d_ws;
  float* x1   = x0 + (size_t)NB * 64 * TLEN;
  float* skip = x1 + (size_t)NB * 64 * TLEN;

  wn_causal_k<<<dim3(NB * TLEN / 256), dim3(256), 0, stream>>>(y, cw, cb, x0);

  float* xi = x0;
  float* xo = x1;
  for (int i = 0; i < NLAYER; ++i) {
    int d = 1 << (i % 10);
    wn_layer_k<<<dim3(NB * TLEN / 64), dim3(256), 0, stream>>>(
        xi, xo, skip, filt + (size_t)i * 8192, gate + (size_t)i * 8192,
        resw + (size_t)i * 4096, skipw + (size_t)i * 16384, d, (i == 0) ? 1 : 0);
    float* tmp = xi; xi = xo; xo = tmp;
  }

  wn_end_k<<<dim3(NB * TLEN / 32), dim3(256), 0, stream>>>(skip, w1, b1, w2,
                                                           b2, out);
}

// Round 3
// 3521.326 us; speedup vs baseline: 3.7167x; 3.7167x over previous
//
#include <hip/hip_runtime.h>

#define TLEN 32768
#define NB 4
#define NLAYER 30
#define TC 8192
#define LOEXT 4032
#define CEXT (TC + LOEXT)          // 12224
#define NXT ((size_t)NB * CEXT * 64)

typedef short bf16x8 __attribute__((ext_vector_type(8)));
typedef float f32x16 __attribute__((ext_vector_type(16)));
#define MFMA32(a, b, c) __builtin_amdgcn_mfma_f32_32x32x16_bf16(a, b, c, 0, 0, 0)

__device__ __forceinline__ unsigned short bfh(float x) {
  unsigned int u = __float_as_uint(x);
  return (unsigned short)((u + 0x7fffu + ((u >> 16) & 1u)) >> 16);
}
__device__ __forceinline__ void fsplit(float x, unsigned short& h, unsigned short& l) {
  unsigned int u = __float_as_uint(x);
  unsigned int hb = (u + 0x7fffu + ((u >> 16) & 1u)) & 0xffff0000u;
  h = (unsigned short)(hb >> 16);
  l = bfh(x - __uint_as_float(hb));
}
__device__ __forceinline__ float bflo(unsigned int p) { return __uint_as_float(p << 16); }
__device__ __forceinline__ float bfhi2(unsigned int p) { return __uint_as_float(p & 0xffff0000u); }

__device__ __forceinline__ void split4(float4 v, uint2& h, uint2& l) {
  unsigned short h0, l0, h1, l1, h2, l2, h3, l3;
  fsplit(v.x, h0, l0); fsplit(v.y, h1, l1);
  fsplit(v.z, h2, l2); fsplit(v.w, h3, l3);
  h.x = (unsigned int)h0 | ((unsigned int)h1 << 16);
  h.y = (unsigned int)h2 | ((unsigned int)h3 << 16);
  l.x = (unsigned int)l0 | ((unsigned int)l1 << 16);
  l.y = (unsigned int)l2 | ((unsigned int)l3 << 16);
}
__device__ __forceinline__ bf16x8 asb(uint4 v) {
  union { uint4 u; bf16x8 b; } x; x.u = v; return x.b;
}
__device__ __forceinline__ bf16x8 asb2(uint2 a, uint2 b) {
  union { uint4 u; bf16x8 v; } x;
  x.u.x = a.x; x.u.y = a.y; x.u.z = b.x; x.u.w = b.y; return x.v;
}
__device__ __forceinline__ float fast_sigmoid(float x) { return 1.0f / (1.0f + __expf(-x)); }
__device__ __forceinline__ float fast_tanh(float x) { return 1.0f - 2.0f / (1.0f + __expf(2.0f * x)); }

// ---------------- prep ----------------

// chunk-local causal conv: xt[b][ti][r] = cw[r]*y[b][base+ti] + cb[r]
__global__ __launch_bounds__(256) void wn_causal_k(
    const float* __restrict__ y, const float* __restrict__ cw,
    const float* __restrict__ cb, float* __restrict__ xt, int base) {
  int ti = blockIdx.x * 64 + (threadIdx.x >> 2);
  int cg = (threadIdx.x & 3) << 4;
  int b = blockIdx.y;
  float yv = y[(size_t)b * TLEN + base + ti];
  float* o = xt + ((size_t)b * CEXT + ti) * 64 + cg;
#pragma unroll
  for (int j = 0; j < 4; ++j) {
    float4 w = *(const float4*)(cw + cg + 4 * j);
    float4 bb = *(const float4*)(cb + cg + 4 * j);
    float4 v; v.x = w.x * yv + bb.x; v.y = w.y * yv + bb.y;
    v.z = w.z * yv + bb.z; v.w = w.w * yv + bb.w;
    *(float4*)(o + 4 * j) = v;
  }
}

// filt/gate: [d][r*2+tap] -> [d][tap*64+r], split hi/lo
__global__ __launch_bounds__(256) void wn_prep_fg_k(
    const float* __restrict__ filt, const float* __restrict__ gate,
    unsigned short* __restrict__ fH, unsigned short* __restrict__ fL,
    unsigned short* __restrict__ gH, unsigned short* __restrict__ gL) {
  int id = blockIdx.x * 256 + threadIdx.x;  // 30*64*64
  int r = id & 63, d = (id >> 6) & 63, i = id >> 12;
  size_t sb = (size_t)i * 8192 + d * 128;
  unsigned short h, l;
#pragma unroll
  for (int tap = 0; tap < 2; ++tap) {
    size_t di = sb + tap * 64 + r;
    fsplit(filt[sb + r * 2 + tap], h, l); fH[di] = h; fL[di] = l;
    fsplit(gate[sb + r * 2 + tap], h, l); gH[di] = h; gL[di] = l;
  }
}

__global__ __launch_bounds__(256) void wn_split_k(
    const float* __restrict__ src, unsigned short* __restrict__ dH,
    unsigned short* __restrict__ dL) {
  int id = blockIdx.x * 256 + threadIdx.x;
  unsigned short h, l;
  fsplit(src[id], h, l);
  dH[id] = h; dL[id] = l;
}

// ---------------- layer kernel (chunk-local) ----------------
// Xs row stride 260 shorts (130 words ≡ 2 mod 32 → 2-way banks, free).
// k layout: hi: tap0 r[0..64) , tap1 r[64..128); lo at +128.
__global__ __launch_bounds__(256, 2) void wn_layer_k(
    const float* __restrict__ xin, float* __restrict__ xout,
    unsigned short* __restrict__ outp,  // [NB][TC][64] bf16 (this layer, this chunk)
    const unsigned short* __restrict__ fH, const unsigned short* __restrict__ fL,
    const unsigned short* __restrict__ gH, const unsigned short* __restrict__ gL,
    const unsigned short* __restrict__ rH, const unsigned short* __restrict__ rL,
    int dil, int ti_start, int lo) {
  __shared__ unsigned short Xs[64 * 260];
  __shared__ unsigned short Os[64 * 132];  // [t][d hi 0..64, lo 64..128]

  const int tid = threadIdx.x;
  const int lane = tid & 63, wave = tid >> 6;
  const int q = lane >> 5, ln = lane & 31;
  const int b = blockIdx.y;
  const int ti0 = ti_start + (int)blockIdx.x * 64;
  const float* xb = xin + (size_t)b * CEXT * 64;

  // ---- stage X tile ----
  {
    int row = tid >> 2, cg = (tid & 3) << 4;
    const float* src = xb + (size_t)(ti0 + row) * 64 + cg;
    unsigned short* dh = &Xs[row * 260 + 64 + cg];
    unsigned short* dl = &Xs[row * 260 + 192 + cg];
#pragma unroll
    for (int j = 0; j < 4; ++j) {
      float4 v = *(const float4*)(src + 4 * j);
      uint2 h, l; split4(v, h, l);
      *(uint2*)(dh + 4 * j) = h; *(uint2*)(dl + 4 * j) = l;
    }
    int ts = ti0 + row - dil;
    dh = &Xs[row * 260 + cg];
    dl = &Xs[row * 260 + 128 + cg];
    if (ts >= 0) {
      const float* s2 = xb + (size_t)ts * 64 + cg;
#pragma unroll
      for (int j = 0; j < 4; ++j) {
        float4 v = *(const float4*)(s2 + 4 * j);
        uint2 h, l; split4(v, h, l);
        *(uint2*)(dh + 4 * j) = h; *(uint2*)(dl + 4 * j) = l;
      }
    } else {
      uint2 z; z.x = 0; z.y = 0;
#pragma unroll
      for (int j = 0; j < 4; ++j) { *(uint2*)(dh + 4 * j) = z; *(uint2*)(dl + 4 * j) = z; }
    }
  }

  const int dblk = wave >> 1, tblk = wave & 1;
  const int arow = dblk * 32 + ln;

  // conv A-frags register-resident
  uint4 afh[8], afl[8], agh[8], agl[8];
  {
    const uint4* pfh = (const uint4*)fH;
    const uint4* pfl = (const uint4*)fL;
    const uint4* pgh = (const uint4*)gH;
    const uint4* pgl = (const uint4*)gL;
#pragma unroll
    for (int kc = 0; kc < 8; ++kc) {
      int ai = arow * 16 + kc * 2 + q;
      afh[kc] = pfh[ai]; afl[kc] = pfl[ai];
      agh[kc] = pgh[ai]; agl[kc] = pgl[ai];
    }
  }
  __syncthreads();

  f32x16 accF, accG;
#pragma unroll
  for (int i = 0; i < 16; ++i) { accF[i] = 0.f; accG[i] = 0.f; }

  const unsigned short* xrow = &Xs[(tblk * 32 + ln) * 260];
#pragma unroll
  for (int kc = 0; kc < 8; ++kc) {
    uint2 h0 = *(const uint2*)(xrow + kc * 16 + q * 8);
    uint2 h1 = *(const uint2*)(xrow + kc * 16 + q * 8 + 4);
    uint2 l0 = *(const uint2*)(xrow + 128 + kc * 16 + q * 8);
    uint2 l1 = *(const uint2*)(xrow + 128 + kc * 16 + q * 8 + 4);
    bf16x8 bh = asb2(h0, h1), bl = asb2(l0, l1);
    accF = MFMA32(asb(afh[kc]), bh, accF);
    accF = MFMA32(asb(afh[kc]), bl, accF);
    accF = MFMA32(asb(afl[kc]), bh, accF);
    accG = MFMA32(asb(agh[kc]), bh, accG);
    accG = MFMA32(asb(agh[kc]), bl, accG);
    accG = MFMA32(asb(agl[kc]), bh, accG);
  }

  // ---- activation -> Os (hi/lo) + global outs (bf16 hi) ----
  {
    int trow = tblk * 32 + ln;
    unsigned short* orow = &Os[trow * 132 + dblk * 32];
    bool wout = (ti0 >= lo);
    unsigned short* gout = outp + ((size_t)b * TC + (ti0 - lo + trow)) * 64 + dblk * 32;
#pragma unroll
    for (int g = 0; g < 4; ++g) {
      int dofs = 8 * g + 4 * q;
      unsigned short oh[4], ol[4];
#pragma unroll
      for (int j = 0; j < 4; ++j) {
        float f = fast_tanh(accF[g * 4 + j]) * fast_sigmoid(accG[g * 4 + j]);
        fsplit(f, oh[j], ol[j]);
      }
      uint2 hv, lv;
      hv.x = (unsigned int)oh[0] | ((unsigned int)oh[1] << 16);
      hv.y = (unsigned int)oh[2] | ((unsigned int)oh[3] << 16);
      lv.x = (unsigned int)ol[0] | ((unsigned int)ol[1] << 16);
      lv.y = (unsigned int)ol[2] | ((unsigned int)ol[3] << 16);
      *(uint2*)(orow + dofs) = hv;
      *(uint2*)(orow + 64 + dofs) = lv;
      if (wout) *(uint2*)(gout + dofs) = hv;
    }
  }
  __syncthreads();

  // ---- residual: xout = x + res_w @ out ----
  {
    const int rblk = wave >> 1, tb2 = wave & 1;
    uint4 arh[4], arl[4];
    const uint4* prh = (const uint4*)rH;
    const uint4* prl = (const uint4*)rL;
#pragma unroll
    for (int kc = 0; kc < 4; ++kc) {
      int ai = (rblk * 32 + ln) * 8 + kc * 2 + q;
      arh[kc] = prh[ai]; arl[kc] = prl[ai];
    }
    f32x16 accR;
#pragma unroll
    for (int i = 0; i < 16; ++i) accR[i] = 0.f;
    const int t = tb2 * 32 + ln;
    const unsigned short* orow = &Os[t * 132];
#pragma unroll
    for (int kc = 0; kc < 4; ++kc) {
      uint2 h0 = *(const uint2*)(orow + kc * 16 + q * 8);
      uint2 h1 = *(const uint2*)(orow + kc * 16 + q * 8 + 4);
      uint2 l0 = *(const uint2*)(orow + 64 + kc * 16 + q * 8);
      uint2 l1 = *(const uint2*)(orow + 64 + kc * 16 + q * 8 + 4);
      bf16x8 bh = asb2(h0, h1), bl = asb2(l0, l1);
      accR = MFMA32(asb(arh[kc]), bh, accR);
      accR = MFMA32(asb(arh[kc]), bl, accR);
      accR = MFMA32(asb(arl[kc]), bh, accR);
    }
    float* xo = xout + ((size_t)b * CEXT + ti0 + t) * 64;
#pragma unroll
    for (int g = 0; g < 4; ++g) {
      int rbase = rblk * 32 + 8 * g + 4 * q;
      uint2 xh = *(const uint2*)&Xs[t * 260 + 64 + rbase];
      uint2 xl = *(const uint2*)&Xs[t * 260 + 192 + rbase];
      float4 v;
      v.x = accR[g * 4 + 0] + bflo(xh.x) + bflo(xl.x);
      v.y = accR[g * 4 + 1] + bfhi2(xh.x) + bfhi2(xl.x);
      v.z = accR[g * 4 + 2] + bflo(xh.y) + bflo(xl.y);
      v.w = accR[g * 4 + 3] + bfhi2(xh.y) + bfhi2(xl.y);
      *(float4*)(xo + rbase) = v;
    }
  }
}

// ---------------- fused skip-sum + head (per chunk) ----------------
__global__ __launch_bounds__(256, 3) void wn_skipend_k(
    const unsigned short* __restrict__ outs,  // [30][NB][TC][64]
    const unsigned short* __restrict__ sH, const unsigned short* __restrict__ sL,
    const unsigned short* __restrict__ e1H, const unsigned short* __restrict__ e1L,
    const float* __restrict__ b1,
    const unsigned short* __restrict__ e2H, const unsigned short* __restrict__ e2L,
    const float* __restrict__ b2, float* __restrict__ out, int c0) {
  __shared__ unsigned short SM[64 * 260];  // Ot (64x68) during skip; Hs (64x260) after

  const int tid = threadIdx.x;
  const int lane = tid & 63, wave = tid >> 6;
  const int q = lane >> 5, ln = lane & 31;
  const int b = blockIdx.y;
  const int tl0 = (int)blockIdx.x * 64;

  f32x16 acc[4];  // [sblk][tt]
#pragma unroll
  for (int a = 0; a < 4; ++a)
#pragma unroll
    for (int i = 0; i < 16; ++i) acc[a][i] = 0.f;

  for (int i = 0; i < NLAYER; ++i) {
    __syncthreads();
    const unsigned short* src = outs + (((size_t)i * NB + b) * TC + tl0) * 64;
#pragma unroll
    for (int s2 = 0; s2 < 2; ++s2) {
      int sl = tid + s2 * 256;
      int row = sl >> 3, c8 = (sl & 7) << 3;
      uint4 v = *(const uint4*)(src + row * 64 + c8);
      uint2 v0; v0.x = v.x; v0.y = v.y;
      uint2 v1; v1.x = v.z; v1.y = v.w;
      *(uint2*)&SM[row * 68 + c8] = v0;
      *(uint2*)&SM[row * 68 + c8 + 4] = v1;
    }
    __syncthreads();
    const uint4* pa = (const uint4*)sH + (size_t)i * 2048;
    const uint4* pl = (const uint4*)sL + (size_t)i * 2048;
#pragma unroll 2
    for (int kc = 0; kc < 4; ++kc) {
#pragma unroll
      for (int sblk = 0; sblk < 2; ++sblk) {
        uint4 ah = pa[(wave * 64 + sblk * 32 + ln) * 8 + kc * 2 + q];
        uint4 al = pl[(wave * 64 + sblk * 32 + ln) * 8 + kc * 2 + q];
#pragma unroll
        for (int tt = 0; tt < 2; ++tt) {
          uint2 b0 = *(const uint2*)&SM[(tt * 32 + ln) * 68 + kc * 16 + q * 8];
          uint2 b1v = *(const uint2*)&SM[(tt * 32 + ln) * 68 + kc * 16 + q * 8 + 4];
          bf16x8 bb = asb2(b0, b1v);
          acc[sblk * 2 + tt] = MFMA32(asb(ah), bb, acc[sblk * 2 + tt]);
          acc[sblk * 2 + tt] = MFMA32(asb(al), bb, acc[sblk * 2 + tt]);
        }
      }
    }
  }
  __syncthreads();
  // h = relu(skip) -> Hs bf16 (row stride 260)
#pragma unroll
  for (int sblk = 0; sblk < 2; ++sblk)
#pragma unroll
    for (int tt = 0; tt < 2; ++tt) {
      int t = tt * 32 + ln;
#pragma unroll
      for (int g = 0; g < 4; ++g) {
        int s = wave * 64 + sblk * 32 + 8 * g + 4 * q;
        unsigned short h0 = bfh(fmaxf(acc[sblk * 2 + tt][g * 4 + 0], 0.f));
        unsigned short h1 = bfh(fmaxf(acc[sblk * 2 + tt][g * 4 + 1], 0.f));
        unsigned short h2 = bfh(fmaxf(acc[sblk * 2 + tt][g * 4 + 2], 0.f));
        unsigned short h3 = bfh(fmaxf(acc[sblk * 2 + tt][g * 4 + 3], 0.f));
        uint2 hv;
        hv.x = (unsigned int)h0 | ((unsigned int)h1 << 16);
        hv.y = (unsigned int)h2 | ((unsigned int)h3 << 16);
        *(uint2*)&SM[t * 260 + s] = hv;
      }
    }
  __syncthreads();

  // e1: acc = e1 @ h  (2-term weights)
#pragma unroll
  for (int a = 0; a < 4; ++a)
#pragma unroll
    for (int i = 0; i < 16; ++i) acc[a][i] = 0.f;
  const uint4* p1h = (const uint4*)e1H;
  const uint4* p1l = (const uint4*)e1L;
#pragma unroll 4
  for (int kc = 0; kc < 16; ++kc) {
#pragma unroll
    for (int ot = 0; ot < 2; ++ot) {
      uint4 ah = p1h[(wave * 64 + ot * 32 + ln) * 32 + kc * 2 + q];
      uint4 al = p1l[(wave * 64 + ot * 32 + ln) * 32 + kc * 2 + q];
#pragma unroll
      for (int tt = 0; tt < 2; ++tt) {
        uint2 b0 = *(const uint2*)&SM[(tt * 32 + ln) * 260 + kc * 16 + q * 8];
        uint2 b1v = *(const uint2*)&SM[(tt * 32 + ln) * 260 + kc * 16 + q * 8 + 4];
        bf16x8 bb = asb2(b0, b1v);
        acc[ot * 2 + tt] = MFMA32(asb(ah), bb, acc[ot * 2 + tt]);
        acc[ot * 2 + tt] = MFMA32(asb(al), bb, acc[ot * 2 + tt]);
      }
    }
  }
  __syncthreads();
  // h2 = relu(acc + b1) -> Hs
#pragma unroll
  for (int ot = 0; ot < 2; ++ot)
#pragma unroll
    for (int tt = 0; tt < 2; ++tt) {
      int t = tt * 32 + ln;
#pragma unroll
      for (int g = 0; g < 4; ++g) {
        int o = wave * 64 + ot * 32 + 8 * g + 4 * q;
        float4 bb = *(const float4*)(b1 + o);
        unsigned short h0 = bfh(fmaxf(acc[ot * 2 + tt][g * 4 + 0] + bb.x, 0.f));
        unsigned short h1 = bfh(fmaxf(acc[ot * 2 + tt][g * 4 + 1] + bb.y, 0.f));
        unsigned short h2 = bfh(fmaxf(acc[ot * 2 + tt][g * 4 + 2] + bb.z, 0.f));
        unsigned short h3 = bfh(fmaxf(acc[ot * 2 + tt][g * 4 + 3] + bb.w, 0.f));
        uint2 hv;
        hv.x = (unsigned int)h0 | ((unsigned int)h1 << 16);
        hv.y = (unsigned int)h2 | ((unsigned int)h3 << 16);
        *(uint2*)&SM[t * 260 + o] = hv;
      }
    }
  __syncthreads();

  // e2: acc = e2 @ h2
#pragma unroll
  for (int a = 0; a < 4; ++a)
#pragma unroll
    for (int i = 0; i < 16; ++i) acc[a][i] = 0.f;
  const uint4* p2h = (const uint4*)e2H;
  const uint4* p2l = (const uint4*)e2L;
#pragma unroll 4
  for (int kc = 0; kc < 16; ++kc) {
#pragma unroll
    for (int ot = 0; ot < 2; ++ot) {
      uint4 ah = p2h[(wave * 64 + ot * 32 + ln) * 32 + kc * 2 + q];
      uint4 al = p2l[(wave * 64 + ot * 32 + ln) * 32 + kc * 2 + q];
#pragma unroll
      for (int tt = 0; tt < 2; ++tt) {
        uint2 b0 = *(const uint2*)&SM[(tt * 32 + ln) * 260 + kc * 16 + q * 8];
        uint2 b1v = *(const uint2*)&SM[(tt * 32 + ln) * 260 + kc * 16 + q * 8 + 4];
        bf16x8 bb = asb2(b0, b1v);
        acc[ot * 2 + tt] = MFMA32(asb(ah), bb, acc[ot * 2 + tt]);
        acc[ot * 2 + tt] = MFMA32(asb(al), bb, acc[ot * 2 + tt]);
      }
    }
  }
  // final store: out[b][c0+tl0+t][c] = acc + b2
#pragma unroll
  for (int ot = 0; ot < 2; ++ot)
#pragma unroll
    for (int tt = 0; tt < 2; ++tt) {
      int t = tt * 32 + ln;
      float* op = out + ((size_t)b * TLEN + c0 + tl0 + t) * 256;
#pragma unroll
      for (int g = 0; g < 4; ++g) {
        int o = wave * 64 + ot * 32 + 8 * g + 4 * q;
        float4 bb = *(const float4*)(b2 + o);
        float4 v;
        v.x = acc[ot * 2 + tt][g * 4 + 0] + bb.x;
        v.y = acc[ot * 2 + tt][g * 4 + 1] + bb.y;
        v.z = acc[ot * 2 + tt][g * 4 + 2] + bb.z;
        v.w = acc[ot * 2 + tt][g * 4 + 3] + bb.w;
        *(float4*)(op + o) = v;
      }
    }
}

extern "C" void kernel_launch(void* const* d_in, const int* in_sizes, int n_in,
                              void* d_out, int out_size, void* d_ws,
                              size_t ws_size, hipStream_t stream) {
  (void)in_sizes; (void)n_in; (void)out_size; (void)ws_size;
  const float* y     = (const float*)d_in[0];
  const float* cw    = (const float*)d_in[1];
  const float* cb    = (const float*)d_in[2];
  const float* filt  = (const float*)d_in[3];
  const float* gate  = (const float*)d_in[4];
  const float* resw  = (const float*)d_in[5];
  const float* skipw = (const float*)d_in[6];
  const float* w1    = (const float*)d_in[7];
  const float* b1    = (const float*)d_in[8];
  const float* w2    = (const float*)d_in[9];
  const float* b2    = (const float*)d_in[10];
  float* out = (float*)d_out;

  // ws: xtA | xtB (chunk-local fp32 x) | outs (chunk bf16) | weight splits  ~156 MB
  float* xtA = (float*)d_ws;
  float* xtB = xtA + NXT;
  unsigned short* outs = (unsigned short*)(xtB + NXT);
  const size_t outsN = (size_t)NLAYER * NB * TC * 64;
  unsigned short* wb = outs + outsN;
  const size_t nFG = (size_t)NLAYER * 8192;
  const size_t nRes = (size_t)NLAYER * 4096;
  const size_t nSkip = (size_t)NLAYER * 16384;
  const size_t nE = 65536;
  unsigned short* fH = wb;            unsigned short* fL = fH + nFG;
  unsigned short* gH = fL + nFG;      unsigned short* gL = gH + nFG;
  unsigned short* rH = gL + nFG;      unsigned short* rL = rH + nRes;
  unsigned short* sH = rL + nRes;     unsigned short* sL = sH + nSkip;
  unsigned short* e1H = sL + nSkip;   unsigned short* e1L = e1H + nE;
  unsigned short* e2H = e1L + nE;     unsigned short* e2L = e2H + nE;

  wn_prep_fg_k<<<dim3(NLAYER * 64 * 64 / 256), dim3(256), 0, stream>>>(
      filt, gate, fH, fL, gH, gL);
  wn_split_k<<<dim3(nRes / 256), dim3(256), 0, stream>>>(resw, rH, rL);
  wn_split_k<<<dim3(nSkip / 256), dim3(256), 0, stream>>>(skipw, sH, sL);
  wn_split_k<<<dim3(nE / 256), dim3(256), 0, stream>>>(w1, e1H, e1L);
  wn_split_k<<<dim3(nE / 256), dim3(256), 0, stream>>>(w2, e2H, e2L);

  // per-layer halo (valid-region chain), 64-aligned
  int P[NLAYER];
  P[NLAYER - 1] = 0;
  for (int i = NLAYER - 1; i >= 1; --i) {
    int d = 1 << (i % 10);
    P[i - 1] = ((P[i] + d + 63) / 64) * 64;
  }
  // P[0]+d0 rounded = LOEXT (4032); static assert via comment.

  for (int c = 0; c < 4; ++c) {
    int c0 = c * TC;
    int lo = (c == 0) ? 0 : LOEXT;
    int ext = TC + lo;
    int base = c0 - lo;
    wn_causal_k<<<dim3(ext / 64, NB), dim3(256), 0, stream>>>(y, cw, cb, xtA, base);
    float* xi = xtA;
    float* xo = xtB;
    for (int i = 0; i < NLAYER; ++i) {
      int d = 1 << (i % 10);
      int Pe = (c == 0) ? 0 : P[i];
      int nt = TC + Pe;
      wn_layer_k<<<dim3(nt / 64, NB), dim3(256), 0, stream>>>(
          xi, xo, outs + (size_t)i * NB * TC * 64,
          fH + (size_t)i * 8192, fL + (size_t)i * 8192,
          gH + (size_t)i * 8192, gL + (size_t)i * 8192,
          rH + (size_t)i * 4096, rL + (size_t)i * 4096,
          d, lo - Pe, lo);
      float* tmp = xi; xi = xo; xo = tmp;
    }
    wn_skipend_k<<<dim3(TC / 64, NB), dim3(256), 0, stream>>>(
        outs, sH, sL, e1H, e1L, b1, e2H, e2L, b2, out, c0);
  }
}